// Round 1
// baseline (247.339 us; speedup 1.0000x reference)
//
#include <hip/hip_runtime.h>
#include <math.h>

// Problem constants
#define NPIX    65536      // 256*256 pixels per camera
#define NBINS   64
#define NBATCH  32         // B*C = 4*8
#define SPLIT   32         // pixel-chunks per batch
#define BLOCKT  256
#define PXPT    4          // pixels per thread per iteration
#define ITERS   (NPIX / SPLIT / (BLOCKT * PXPT))   // = 2
#define NSUB    8          // LDS sub-histograms to spread atomic collisions
#define HSTRIDE 66         // 64 bins + dump slot (64) + pad
#define LDSN    (NSUB * HSTRIDE)

// exp(3) for the sigmoid chain; 3*log2(e) for exp2-based exponential
#define E3      20.085536923187668f
#define THREE_LOG2E 4.328085122666891f

__device__ __forceinline__ void process_pixel(
    float nx, float ny, float nz,          // normal (raw, un-normalized)
    float ix, float iy, float iz,          // intersection (camera space)
    float fx, float fy, float fz,          // film_mask (unit vector)
    float cm,                              // cos_mask
    float* __restrict__ hist, int subOff,
    float kconst, float lmask_c, float inv_bin)
{
    // cosine foreshortening, clipped to [0,1]
    float dt = fx * nx + fy * ny + fz * nz;
    dt = fminf(fmaxf(dt, 0.0f), 1.0f);

    // laser geometry: origin offset by 2*DCS = 0.002 along +x
    float lx = ix - 0.002f;
    float lxy2 = lx * lx + iy * iy;
    float l2 = lxy2 + iz * iz;             // laser_distance^2
    float ld = __builtin_amdgcn_sqrtf(l2);
    float invz2 = __builtin_amdgcn_rcpf(iz * iz);
    // laser_mask = exp(-tan^2/(2 sig^2)) computed as exp2(lmask_c * tan^2)
    float lm = __builtin_amdgcn_exp2f(lmask_c * lxy2 * invz2);

    float cm3 = cm * cm * cm;
    float r = dt * lm * kconst * cm3 * __builtin_amdgcn_rcpf(l2);

    float di = __builtin_amdgcn_sqrtf(ix * ix + iy * iy + iz * iz);
    float d = (di + ld) * 0.5f * inv_bin;  // depth in bin units

    // 16-bin window [floor(d)-7, floor(d)+8]; tail error ~e^-21, negligible
    float j0f = floorf(d) - 7.0f;
    int j0 = (int)j0f;
    // e = exp(-3*(d - j0)) ; chain e *= e^3 to walk the window
    float e = __builtin_amdgcn_exp2f((j0f - d) * THREE_LOG2E);
    float sPrev = __builtin_amdgcn_rcpf(1.0f + e);   // sigmoid(3*(d-j0))
    #pragma unroll
    for (int m = 0; m < 16; ++m) {
        e *= E3;
        float sCur = __builtin_amdgcn_rcpf(1.0f + e); // sigmoid(3*(d-j0-m-1))
        int k = j0 + m;
        // branchless: out-of-range bins go to dump slot 64
        int idx = ((unsigned)k < 64u) ? (subOff + k) : (subOff + 64);
        unsafeAtomicAdd(&hist[idx], r * (sPrev - sCur));
        sPrev = sCur;
    }
}

__global__ __launch_bounds__(BLOCKT) void spad_hist_kernel(
    const float* __restrict__ normals,      // [32, 65536, 3]
    const float* __restrict__ inters,       // [32, 65536, 3]
    const float* __restrict__ film,         // [65536, 3]
    const float* __restrict__ cosm,         // [65536]
    float* __restrict__ ws,                 // [1024, 64] block partials
    float kconst, float lmask_c, float inv_bin)
{
    __shared__ float hist[LDSN];
    const int tid = threadIdx.x;
    for (int i = tid; i < LDSN; i += BLOCKT) hist[i] = 0.0f;
    __syncthreads();

    // consecutive blocks share a pixel chunk (same film/cos lines -> L2 reuse)
    const int b = blockIdx.x & (NBATCH - 1);
    const int chunk = blockIdx.x / NBATCH;
    const int pix0 = chunk * (NPIX / SPLIT);
    const int subOff = (tid & (NSUB - 1)) * HSTRIDE;

    #pragma unroll
    for (int it = 0; it < ITERS; ++it) {
        const int pp = pix0 + (it * BLOCKT + tid) * PXPT;
        const float4* n4 = (const float4*)(normals + ((size_t)b * NPIX + pp) * 3);
        const float4* i4 = (const float4*)(inters  + ((size_t)b * NPIX + pp) * 3);
        const float4* f4 = (const float4*)(film + (size_t)pp * 3);
        const float4  c4 = *(const float4*)(cosm + pp);
        float4 n0 = n4[0], n1 = n4[1], n2 = n4[2];
        float4 i0 = i4[0], i1 = i4[1], i2 = i4[2];
        float4 f0 = f4[0], f1 = f4[1], f2 = f4[2];

        process_pixel(n0.x, n0.y, n0.z, i0.x, i0.y, i0.z, f0.x, f0.y, f0.z, c4.x,
                      hist, subOff, kconst, lmask_c, inv_bin);
        process_pixel(n0.w, n1.x, n1.y, i0.w, i1.x, i1.y, f0.w, f1.x, f1.y, c4.y,
                      hist, subOff, kconst, lmask_c, inv_bin);
        process_pixel(n1.z, n1.w, n2.x, i1.z, i1.w, i2.x, f1.z, f1.w, f2.x, c4.z,
                      hist, subOff, kconst, lmask_c, inv_bin);
        process_pixel(n2.y, n2.z, n2.w, i2.y, i2.z, i2.w, f2.y, f2.z, f2.w, c4.w,
                      hist, subOff, kconst, lmask_c, inv_bin);
    }
    __syncthreads();

    // reduce sub-histograms; write block partial to workspace (no global atomics)
    if (tid < NBINS) {
        float s = 0.0f;
        #pragma unroll
        for (int ss = 0; ss < NSUB; ++ss) s += hist[ss * HSTRIDE + tid];
        ws[(size_t)blockIdx.x * NBINS + tid] = s;
    }
}

__global__ __launch_bounds__(BLOCKT) void spad_reduce_kernel(
    const float* __restrict__ ws, float* __restrict__ out)
{
    const int o = blockIdx.x * BLOCKT + threadIdx.x;  // 0..2047 -> (b, k)
    const int b = o >> 6;
    const int k = o & 63;
    float s = 0.0f;
    #pragma unroll
    for (int c = 0; c < SPLIT; ++c)
        s += ws[((size_t)(c * NBATCH + b)) * NBINS + k];
    out[o] = s;   // every element written -> no memset needed
}

extern "C" void kernel_launch(void* const* d_in, const int* in_sizes, int n_in,
                              void* d_out, int out_size, void* d_ws, size_t ws_size,
                              hipStream_t stream) {
    const float* normals = (const float*)d_in[0];
    const float* inters  = (const float*)d_in[1];
    const float* film    = (const float*)d_in[2];
    const float* cosm    = (const float*)d_in[3];
    float* out = (float*)d_out;
    float* ws  = (float*)d_ws;   // needs 1024*64*4 = 256 KiB

    // host-side double-precision constants (argument setup; capture-safe)
    const double fov_rad = 33.0 * M_PI / 180.0;
    const double width = 2.0 * tan(fov_rad / 2.0);
    const double kconst_d = width * width / M_PI / 65536.0;       // width^2/pi/R^2
    const double sig = tan(21.5 * M_PI / 180.0) / 1.4;
    const double log2e = 1.4426950408889634;
    const double lmask_c_d = -log2e / (2.0 * sig * sig);          // exp2 scale
    const double inv_bin_d = 1.0 / 0.0136;

    spad_hist_kernel<<<NBATCH * SPLIT, BLOCKT, 0, stream>>>(
        normals, inters, film, cosm, ws,
        (float)kconst_d, (float)lmask_c_d, (float)inv_bin_d);

    spad_reduce_kernel<<<(NBATCH * NBINS) / BLOCKT, BLOCKT, 0, stream>>>(ws, out);
}

// Round 2
// 205.262 us; speedup vs baseline: 1.2050x; 1.2050x over previous
//
#include <hip/hip_runtime.h>
#include <math.h>

// Problem constants
#define NPIX    65536      // 256*256 pixels per camera
#define NBINS   64
#define NBATCH  32         // B*C = 4*8
#define SPLIT   32         // pixel-chunks per batch
#define BLOCKT  256
#define PXPT    4          // pixels per thread per iteration
#define ITERS   (NPIX / SPLIT / (BLOCKT * PXPT))   // = 2
#define NSUB    64         // one sub-histogram PER LANE: zero intra-wave atomic contention
#define HSTRIDE 65         // 64 bins + dump slot(64); odd -> bank=(lane+k)%32, 2-way max (free)
#define LDSN    (NSUB * HSTRIDE)
#define WIN     12         // soft-bin window; tail <= 19*e^-18 ~ 3e-7 relative

// exp(3) for the sigmoid chain; 3*log2(e) for exp2-based exponential
#define E3      20.085536923187668f
#define THREE_LOG2E 4.328085122666891f

__device__ __forceinline__ void process_pixel(
    float nx, float ny, float nz,          // normal (raw, un-normalized)
    float ix, float iy, float iz,          // intersection (camera space)
    float fx, float fy, float fz,          // film_mask (unit vector)
    float cm,                              // cos_mask
    float* __restrict__ hist, int subOff,
    float kconst, float lmask_c, float inv_bin)
{
    // cosine foreshortening, clipped to [0,1]
    float dt = fx * nx + fy * ny + fz * nz;
    dt = fminf(fmaxf(dt, 0.0f), 1.0f);

    // laser geometry: origin offset by 2*DCS = 0.002 along +x
    float lx = ix - 0.002f;
    float lxy2 = lx * lx + iy * iy;
    float l2 = lxy2 + iz * iz;             // laser_distance^2
    float ld = __builtin_amdgcn_sqrtf(l2);
    float invz2 = __builtin_amdgcn_rcpf(iz * iz);
    // laser_mask = exp(-tan^2/(2 sig^2)) computed as exp2(lmask_c * tan^2)
    float lm = __builtin_amdgcn_exp2f(lmask_c * lxy2 * invz2);

    float cm3 = cm * cm * cm;
    float r = dt * lm * kconst * cm3 * __builtin_amdgcn_rcpf(l2);

    float di = __builtin_amdgcn_sqrtf(ix * ix + iy * iy + iz * iz);
    float d = (di + ld) * 0.5f * inv_bin;  // depth in bin units

    // WIN-bin window [floor(d)-5, floor(d)+6]
    float j0f = floorf(d) - 5.0f;
    int j0 = (int)j0f;
    // e = exp(3*(j0-d)); chain e *= e^3 to walk the window
    float e = __builtin_amdgcn_exp2f((j0f - d) * THREE_LOG2E);
    float sPrev = __builtin_amdgcn_rcpf(1.0f + e);   // sigmoid(3*(d-j0))
    #pragma unroll
    for (int m = 0; m < WIN; ++m) {
        e *= E3;
        float sCur = __builtin_amdgcn_rcpf(1.0f + e); // sigmoid(3*(d-j0-m-1))
        int k = j0 + m;
        // branchless: out-of-range bins go to dump slot 64
        int idx = ((unsigned)k < 64u) ? (subOff + k) : (subOff + 64);
        unsafeAtomicAdd(&hist[idx], r * (sPrev - sCur));
        sPrev = sCur;
    }
}

__global__ __launch_bounds__(BLOCKT) void spad_hist_kernel(
    const float* __restrict__ normals,      // [32, 65536, 3]
    const float* __restrict__ inters,       // [32, 65536, 3]
    const float* __restrict__ film,         // [65536, 3]
    const float* __restrict__ cosm,         // [65536]
    float* __restrict__ ws,                 // [1024, 64] block partials
    float kconst, float lmask_c, float inv_bin)
{
    __shared__ float hist[LDSN];
    const int tid = threadIdx.x;
    for (int i = tid; i < LDSN; i += BLOCKT) hist[i] = 0.0f;
    __syncthreads();

    // consecutive blocks share a pixel chunk (same film/cos lines -> L2 reuse)
    const int b = blockIdx.x & (NBATCH - 1);
    const int chunk = blockIdx.x / NBATCH;
    const int pix0 = chunk * (NPIX / SPLIT);
    // one private sub-histogram per lane: no intra-wave same-address serialization
    const int subOff = (tid & 63) * HSTRIDE;

    #pragma unroll
    for (int it = 0; it < ITERS; ++it) {
        const int pp = pix0 + (it * BLOCKT + tid) * PXPT;
        const float4* n4 = (const float4*)(normals + ((size_t)b * NPIX + pp) * 3);
        const float4* i4 = (const float4*)(inters  + ((size_t)b * NPIX + pp) * 3);
        const float4* f4 = (const float4*)(film + (size_t)pp * 3);
        const float4  c4 = *(const float4*)(cosm + pp);
        float4 n0 = n4[0], n1 = n4[1], n2 = n4[2];
        float4 i0 = i4[0], i1 = i4[1], i2 = i4[2];
        float4 f0 = f4[0], f1 = f4[1], f2 = f4[2];

        process_pixel(n0.x, n0.y, n0.z, i0.x, i0.y, i0.z, f0.x, f0.y, f0.z, c4.x,
                      hist, subOff, kconst, lmask_c, inv_bin);
        process_pixel(n0.w, n1.x, n1.y, i0.w, i1.x, i1.y, f0.w, f1.x, f1.y, c4.y,
                      hist, subOff, kconst, lmask_c, inv_bin);
        process_pixel(n1.z, n1.w, n2.x, i1.z, i1.w, i2.x, f1.z, f1.w, f2.x, c4.z,
                      hist, subOff, kconst, lmask_c, inv_bin);
        process_pixel(n2.y, n2.z, n2.w, i2.y, i2.z, i2.w, f2.y, f2.z, f2.w, c4.w,
                      hist, subOff, kconst, lmask_c, inv_bin);
    }
    __syncthreads();

    // reduce sub-histograms; write block partial to workspace (no global atomics)
    if (tid < NBINS) {
        float s = 0.0f;
        #pragma unroll
        for (int ss = 0; ss < NSUB; ++ss) s += hist[ss * HSTRIDE + tid];
        ws[(size_t)blockIdx.x * NBINS + tid] = s;
    }
}

__global__ __launch_bounds__(BLOCKT) void spad_reduce_kernel(
    const float* __restrict__ ws, float* __restrict__ out)
{
    const int o = blockIdx.x * BLOCKT + threadIdx.x;  // 0..2047 -> (b, k)
    const int b = o >> 6;
    const int k = o & 63;
    float s = 0.0f;
    #pragma unroll
    for (int c = 0; c < SPLIT; ++c)
        s += ws[((size_t)(c * NBATCH + b)) * NBINS + k];
    out[o] = s;   // every element written -> no memset needed
}

extern "C" void kernel_launch(void* const* d_in, const int* in_sizes, int n_in,
                              void* d_out, int out_size, void* d_ws, size_t ws_size,
                              hipStream_t stream) {
    const float* normals = (const float*)d_in[0];
    const float* inters  = (const float*)d_in[1];
    const float* film    = (const float*)d_in[2];
    const float* cosm    = (const float*)d_in[3];
    float* out = (float*)d_out;
    float* ws  = (float*)d_ws;   // needs 1024*64*4 = 256 KiB

    // host-side double-precision constants (argument setup; capture-safe)
    const double fov_rad = 33.0 * M_PI / 180.0;
    const double width = 2.0 * tan(fov_rad / 2.0);
    const double kconst_d = width * width / M_PI / 65536.0;       // width^2/pi/R^2
    const double sig = tan(21.5 * M_PI / 180.0) / 1.4;
    const double log2e = 1.4426950408889634;
    const double lmask_c_d = -log2e / (2.0 * sig * sig);          // exp2 scale
    const double inv_bin_d = 1.0 / 0.0136;

    spad_hist_kernel<<<NBATCH * SPLIT, BLOCKT, 0, stream>>>(
        normals, inters, film, cosm, ws,
        (float)kconst_d, (float)lmask_c_d, (float)inv_bin_d);

    spad_reduce_kernel<<<(NBATCH * NBINS) / BLOCKT, BLOCKT, 0, stream>>>(ws, out);
}

// Round 3
// 94.817 us; speedup vs baseline: 2.6086x; 2.1648x over previous
//
#include <hip/hip_runtime.h>
#include <math.h>

// Problem constants
#define NPIX    65536      // 256*256 pixels per camera
#define NBINS   64
#define NBATCH  32         // B*C = 4*8
#define SPLIT   32         // pixel-chunks per batch
#define BLOCKT  128        // 2 waves/block
#define PXPT    4          // pixels per thread per iteration
#define ITERS   (NPIX / SPLIT / (BLOCKT * PXPT))   // = 4 -> 16 px/thread
#define HSTRIDE 65         // 64 bins + pad; bank=(tid+k)%32 -> 2-way max (free)
#define LDSN    (BLOCKT * HSTRIDE)                 // 8320 floats = 33.3 KB
#define WIN     8          // clamped window [j0-3, j0+4]; tail ~1.2e-4 rel -> ~1e-8 abs

// exp(3) for the sigmoid chain; 3*log2(e) for exp2-based exponential
#define E3          20.085536923187668f
#define THREE_LOG2E 4.328085122666891f

__global__ __launch_bounds__(BLOCKT) void spad_hist_kernel(
    const float* __restrict__ normals,      // [32, 65536, 3]
    const float* __restrict__ inters,       // [32, 65536, 3]
    const float* __restrict__ film,         // [65536, 3]
    const float* __restrict__ cosm,         // [65536]
    float* __restrict__ ws,                 // [1024, 64] block partials
    float kconst, float lmask_c, float half_inv_bin)
{
    // THREAD-PRIVATE LDS histograms: no atomics anywhere in the main loop.
    // Accessed directly on the __shared__ array so addrspace(3) is statically
    // known -> ds_read_b32/ds_write_b32, never flat ops.
    __shared__ float hist[LDSN];
    const int tid = threadIdx.x;
    for (int i = tid; i < LDSN; i += BLOCKT) hist[i] = 0.0f;
    __syncthreads();

    const int b = blockIdx.x & (NBATCH - 1);
    const int chunk = blockIdx.x / NBATCH;
    const int pix0 = chunk * (NPIX / SPLIT);
    const int base = tid * HSTRIDE;

    auto accum = [&](float nx, float ny, float nz,
                     float ix, float iy, float iz,
                     float fx, float fy, float fz, float cm) {
        // cosine foreshortening, clipped to [0,1]
        float dt = fx * nx + fy * ny + fz * nz;
        dt = fminf(fmaxf(dt, 0.0f), 1.0f);
        // laser geometry: origin offset by 2*DCS = 0.002 along +x
        float lx = ix - 0.002f;
        float lxy2 = lx * lx + iy * iy;
        float l2 = lxy2 + iz * iz;                  // laser_distance^2
        float ld = __builtin_amdgcn_sqrtf(l2);
        float lm = __builtin_amdgcn_exp2f(lmask_c * lxy2 * __builtin_amdgcn_rcpf(iz * iz));
        float cm3 = cm * cm * cm;
        float r = dt * lm * kconst * cm3 * __builtin_amdgcn_rcpf(l2);
        float di = __builtin_amdgcn_sqrtf(ix * ix + iy * iy + iz * iz);
        float d = (di + ld) * half_inv_bin;         // depth in bin units

        // clamp window start so all WIN slots are in [0,63] and statically
        // distinct (consecutive) -> compiler proves no LDS aliasing in-loop
        int j0 = (int)floorf(d);
        j0 = j0 < 3 ? 3 : (j0 > 59 ? 59 : j0);
        const int k0 = j0 - 3;                      // in [0, 56]
        float e = __builtin_amdgcn_exp2f(((float)k0 - d) * THREE_LOG2E);
        float sPrev = __builtin_amdgcn_rcpf(1.0f + e);  // sigmoid(3*(d-k0))
        const int p = base + k0;
        #pragma unroll
        for (int m = 0; m < WIN; ++m) {
            e *= E3;
            float sCur = __builtin_amdgcn_rcpf(1.0f + e);
            hist[p + m] += r * (sPrev - sCur);      // private -> plain RMW
            sPrev = sCur;
        }
    };

    #pragma unroll
    for (int it = 0; it < ITERS; ++it) {
        const int pp = pix0 + (it * BLOCKT + tid) * PXPT;
        const float4* n4 = (const float4*)(normals + ((size_t)b * NPIX + pp) * 3);
        const float4* i4 = (const float4*)(inters  + ((size_t)b * NPIX + pp) * 3);
        const float4* f4 = (const float4*)(film + (size_t)pp * 3);
        const float4  c4 = *(const float4*)(cosm + pp);
        float4 n0 = n4[0], n1 = n4[1], n2 = n4[2];
        float4 i0 = i4[0], i1 = i4[1], i2 = i4[2];
        float4 f0 = f4[0], f1 = f4[1], f2 = f4[2];

        accum(n0.x, n0.y, n0.z, i0.x, i0.y, i0.z, f0.x, f0.y, f0.z, c4.x);
        accum(n0.w, n1.x, n1.y, i0.w, i1.x, i1.y, f0.w, f1.x, f1.y, c4.y);
        accum(n1.z, n1.w, n2.x, i1.z, i1.w, i2.x, f1.z, f1.w, f2.x, c4.z);
        accum(n2.y, n2.z, n2.w, i2.y, i2.z, i2.w, f2.y, f2.z, f2.w, c4.w);
    }
    __syncthreads();

    // reduce the 128 private histograms; write block partial (no atomics)
    if (tid < NBINS) {
        float s = 0.0f;
        for (int t = 0; t < BLOCKT; ++t) s += hist[t * HSTRIDE + tid];
        ws[(size_t)blockIdx.x * NBINS + tid] = s;
    }
}

__global__ __launch_bounds__(256) void spad_reduce_kernel(
    const float* __restrict__ ws, float* __restrict__ out)
{
    const int o = blockIdx.x * 256 + threadIdx.x;  // 0..2047 -> (b, k)
    const int b = o >> 6;
    const int k = o & 63;
    float s = 0.0f;
    #pragma unroll
    for (int c = 0; c < SPLIT; ++c)
        s += ws[((size_t)(c * NBATCH + b)) * NBINS + k];
    out[o] = s;   // every element written -> no memset needed
}

extern "C" void kernel_launch(void* const* d_in, const int* in_sizes, int n_in,
                              void* d_out, int out_size, void* d_ws, size_t ws_size,
                              hipStream_t stream) {
    const float* normals = (const float*)d_in[0];
    const float* inters  = (const float*)d_in[1];
    const float* film    = (const float*)d_in[2];
    const float* cosm    = (const float*)d_in[3];
    float* out = (float*)d_out;
    float* ws  = (float*)d_ws;   // needs 1024*64*4 = 256 KiB

    // host-side double-precision constants (argument setup; capture-safe)
    const double fov_rad = 33.0 * M_PI / 180.0;
    const double width = 2.0 * tan(fov_rad / 2.0);
    const double kconst_d = width * width / M_PI / 65536.0;       // width^2/pi/R^2
    const double sig = tan(21.5 * M_PI / 180.0) / 1.4;
    const double log2e = 1.4426950408889634;
    const double lmask_c_d = -log2e / (2.0 * sig * sig);          // exp2 scale
    const double half_inv_bin_d = 0.5 / 0.0136;

    spad_hist_kernel<<<NBATCH * SPLIT, BLOCKT, 0, stream>>>(
        normals, inters, film, cosm, ws,
        (float)kconst_d, (float)lmask_c_d, (float)half_inv_bin_d);

    spad_reduce_kernel<<<(NBATCH * NBINS) / 256, 256, 0, stream>>>(ws, out);
}

// Round 4
// 92.992 us; speedup vs baseline: 2.6598x; 1.0196x over previous
//
#include <hip/hip_runtime.h>
#include <math.h>

// Problem constants
#define NPIX    65536      // 256*256 pixels per camera
#define NBINS   64
#define NBATCH  32         // B*C = 4*8
#define SPLIT   32         // pixel-chunks per batch
#define BLOCKT  128        // 2 waves/block
#define PXPT    4          // pixels per thread per iteration
#define ITERS   (NPIX / SPLIT / (BLOCKT * PXPT))   // = 4 -> 16 px/thread
#define HSTRIDE 68         // dwords/thread: 16B-aligned base, bank stride 17 (odd) -> 2-way max
#define LDSN    (BLOCKT * HSTRIDE)                 // 8704 floats = 34.8 KB -> 4 blocks/CU
#define WIN     12         // 4-aligned window, guaranteed [j0-4, j0+4] coverage; tail e^-12

#define THREE_LOG2E 4.328085122666891f

__global__ __launch_bounds__(BLOCKT, 2) void spad_hist_kernel(
    const float* __restrict__ normals,      // [32, 65536, 3]
    const float* __restrict__ inters,       // [32, 65536, 3]
    const float* __restrict__ film,         // [65536, 3]
    const float* __restrict__ cosm,         // [65536]
    float* __restrict__ ws,                 // [1024, 64] block partials
    float kconst, float lmask_c, float half_inv_bin)
{
    // Thread-private LDS histograms, no atomics. 16B-aligned windows -> b128 RMW.
    __shared__ float hist[LDSN];
    const int tid = threadIdx.x;
    {   // zero own region with b128 stores
        float4* h4 = (float4*)&hist[tid * HSTRIDE];
        #pragma unroll
        for (int i = 0; i < HSTRIDE / 4; ++i) h4[i] = make_float4(0.f, 0.f, 0.f, 0.f);
    }
    __syncthreads();

    const int b = blockIdx.x & (NBATCH - 1);
    const int chunk = blockIdx.x / NBATCH;
    const int pix0 = chunk * (NPIX / SPLIT);
    const int base = tid * HSTRIDE;

    // E3^m, m=0..12 — independent scaling breaks the serial exp chain
    const float E3P[13] = {
        1.0f, 20.085536923187668f, 403.4287934927351f, 8103.083927575384f,
        162754.79141900392f, 3269017.372472111f, 65659969.13733051f,
        1318815734.4832146f, 26489122129.843472f, 532048240601.79865f,
        10686474581524.462f, 214643579785916.06f, 4311231547115195.0f };

    #pragma unroll
    for (int it = 0; it < ITERS; ++it) {
        const int pp = pix0 + (it * BLOCKT + tid) * PXPT;
        const float4* n4 = (const float4*)(normals + ((size_t)b * NPIX + pp) * 3);
        const float4* i4 = (const float4*)(inters  + ((size_t)b * NPIX + pp) * 3);
        const float4* f4 = (const float4*)(film + (size_t)pp * 3);
        const float4  c4 = *(const float4*)(cosm + pp);
        float4 n0 = n4[0], n1 = n4[1], n2 = n4[2];
        float4 i0 = i4[0], i1 = i4[1], i2 = i4[2];
        float4 f0 = f4[0], f1 = f4[1], f2 = f4[2];

        // gather 4 pixels into arrays (SoA in registers)
        float NX[4] = {n0.x, n0.w, n1.z, n2.y}, NY[4] = {n0.y, n1.x, n1.w, n2.z},
              NZ[4] = {n0.z, n1.y, n2.x, n2.w};
        float IX[4] = {i0.x, i0.w, i1.z, i2.y}, IY[4] = {i0.y, i1.x, i1.w, i2.z},
              IZ[4] = {i0.z, i1.y, i2.x, i2.w};
        float FX[4] = {f0.x, f0.w, f1.z, f2.y}, FY[4] = {f0.y, f1.x, f1.w, f2.z},
              FZ[4] = {f0.z, f1.y, f2.x, f2.w};
        float CM[4] = {c4.x, c4.y, c4.z, c4.w};

        float R[4];
        int   K0[4];
        float S[4][13];

        // Phase 1: all geometry + all sigmoids (4 independent chains -> ILP)
        #pragma unroll
        for (int p = 0; p < 4; ++p) {
            float dt = FX[p] * NX[p] + FY[p] * NY[p] + FZ[p] * NZ[p];
            dt = fminf(fmaxf(dt, 0.0f), 1.0f);
            float lx = IX[p] - 0.002f;
            float lxy2 = lx * lx + IY[p] * IY[p];
            float l2 = lxy2 + IZ[p] * IZ[p];
            float ld = __builtin_amdgcn_sqrtf(l2);
            float lm = __builtin_amdgcn_exp2f(
                lmask_c * lxy2 * __builtin_amdgcn_rcpf(IZ[p] * IZ[p]));
            float cm3 = CM[p] * CM[p] * CM[p];
            R[p] = dt * lm * kconst * cm3 * __builtin_amdgcn_rcpf(l2);
            float di = __builtin_amdgcn_sqrtf(
                IX[p] * IX[p] + IY[p] * IY[p] + IZ[p] * IZ[p]);
            float d = (di + ld) * half_inv_bin;     // depth in bin units

            int j0 = (int)floorf(d);
            j0 = j0 < 4 ? 4 : (j0 > 56 ? 56 : j0);
            int k0 = (j0 - 4) & ~3;                 // 4-aligned, in [0, 52]
            K0[p] = k0;
            float e0 = __builtin_amdgcn_exp2f(((float)k0 - d) * THREE_LOG2E);
            #pragma unroll
            for (int m = 0; m < 13; ++m)            // independent mul+rcp
                S[p][m] = __builtin_amdgcn_rcpf(1.0f + e0 * E3P[m]);
        }

        // Phase 2: per-pixel b128 RMW (ordered; same-thread windows may alias,
        // DS pipe is in-order per wave so read-after-write is safe)
        #pragma unroll
        for (int p = 0; p < 4; ++p) {
            float4* hp = (float4*)&hist[base + K0[p]];
            float4 a = hp[0], bb = hp[1], c = hp[2];
            float r = R[p];
            a.x  += r * (S[p][0]  - S[p][1]);
            a.y  += r * (S[p][1]  - S[p][2]);
            a.z  += r * (S[p][2]  - S[p][3]);
            a.w  += r * (S[p][3]  - S[p][4]);
            bb.x += r * (S[p][4]  - S[p][5]);
            bb.y += r * (S[p][5]  - S[p][6]);
            bb.z += r * (S[p][6]  - S[p][7]);
            bb.w += r * (S[p][7]  - S[p][8]);
            c.x  += r * (S[p][8]  - S[p][9]);
            c.y  += r * (S[p][9]  - S[p][10]);
            c.z  += r * (S[p][10] - S[p][11]);
            c.w  += r * (S[p][11] - S[p][12]);
            hp[0] = a; hp[1] = bb; hp[2] = c;
        }
    }
    __syncthreads();

    // 3-phase float4 reduction of 128 private histograms
    const int g = tid & 15;      // bin group: bins 4g..4g+3
    const int h = tid >> 4;      // hist subset start
    float4 acc = make_float4(0.f, 0.f, 0.f, 0.f);
    #pragma unroll
    for (int j = 0; j < 16; ++j) {
        float4 v = *(const float4*)&hist[(h + 8 * j) * HSTRIDE + 4 * g];
        acc.x += v.x; acc.y += v.y; acc.z += v.z; acc.w += v.w;
    }
    __syncthreads();
    *(float4*)&hist[tid * 4] = acc;   // partial[h][g] at dword h*64 + 4g
    __syncthreads();
    if (tid < 16) {
        float4 s4 = make_float4(0.f, 0.f, 0.f, 0.f);
        #pragma unroll
        for (int hh = 0; hh < 8; ++hh) {
            float4 v = *(const float4*)&hist[hh * 64 + tid * 4];
            s4.x += v.x; s4.y += v.y; s4.z += v.z; s4.w += v.w;
        }
        *(float4*)&ws[(size_t)blockIdx.x * NBINS + tid * 4] = s4;
    }
}

__global__ __launch_bounds__(256) void spad_reduce_kernel(
    const float* __restrict__ ws, float* __restrict__ out)
{
    const int o = blockIdx.x * 256 + threadIdx.x;  // 0..2047 -> (b, k)
    const int b = o >> 6;
    const int k = o & 63;
    float s = 0.0f;
    #pragma unroll
    for (int c = 0; c < SPLIT; ++c)
        s += ws[((size_t)(c * NBATCH + b)) * NBINS + k];
    out[o] = s;   // every element written -> no memset needed
}

extern "C" void kernel_launch(void* const* d_in, const int* in_sizes, int n_in,
                              void* d_out, int out_size, void* d_ws, size_t ws_size,
                              hipStream_t stream) {
    const float* normals = (const float*)d_in[0];
    const float* inters  = (const float*)d_in[1];
    const float* film    = (const float*)d_in[2];
    const float* cosm    = (const float*)d_in[3];
    float* out = (float*)d_out;
    float* ws  = (float*)d_ws;   // needs 1024*64*4 = 256 KiB

    // host-side double-precision constants (argument setup; capture-safe)
    const double fov_rad = 33.0 * M_PI / 180.0;
    const double width = 2.0 * tan(fov_rad / 2.0);
    const double kconst_d = width * width / M_PI / 65536.0;       // width^2/pi/R^2
    const double sig = tan(21.5 * M_PI / 180.0) / 1.4;
    const double log2e = 1.4426950408889634;
    const double lmask_c_d = -log2e / (2.0 * sig * sig);          // exp2 scale
    const double half_inv_bin_d = 0.5 / 0.0136;

    spad_hist_kernel<<<NBATCH * SPLIT, BLOCKT, 0, stream>>>(
        normals, inters, film, cosm, ws,
        (float)kconst_d, (float)lmask_c_d, (float)half_inv_bin_d);

    spad_reduce_kernel<<<(NBATCH * NBINS) / 256, 256, 0, stream>>>(ws, out);
}

// Round 5
// 92.768 us; speedup vs baseline: 2.6662x; 1.0024x over previous
//
#include <hip/hip_runtime.h>
#include <math.h>

// Problem constants
#define NPIX    65536      // 256*256 pixels per camera
#define NBINS   64
#define NBATCH  32         // B*C = 4*8
#define SPLIT   32         // pixel-chunks per batch
#define BLOCKT  128        // 2 waves/block
#define PXPT    4          // pixels per thread per iteration
#define ITERS   (NPIX / SPLIT / (BLOCKT * PXPT))   // = 4 -> 16 px/thread
#define HSTRIDE 68         // dwords/thread: 16B-aligned base, bank stride (68%32=4, tid*4 spread) -> benign
#define LDSN    (BLOCKT * HSTRIDE)                 // 8704 floats = 34.8 KB -> 4 blocks/CU
#define WIN     8          // 4-aligned window, coverage >= [j0-3, j0+4]; R3-validated absmax ~3e-5

#define THREE_LOG2E 4.328085122666891f

__global__ __launch_bounds__(BLOCKT, 2) void spad_hist_kernel(
    const float* __restrict__ normals,      // [32, 65536, 3]
    const float* __restrict__ inters,       // [32, 65536, 3]
    const float* __restrict__ film,         // [65536, 3]
    const float* __restrict__ cosm,         // [65536]
    float* __restrict__ ws,                 // [1024, 64] block partials
    float kconst, float lmask_c, float half_inv_bin)
{
    // Thread-private LDS histograms, no atomics. 16B-aligned windows -> b128 RMW.
    __shared__ float hist[LDSN];
    const int tid = threadIdx.x;
    {   // zero own region with b128 stores
        float4* h4 = (float4*)&hist[tid * HSTRIDE];
        #pragma unroll
        for (int i = 0; i < HSTRIDE / 4; ++i) h4[i] = make_float4(0.f, 0.f, 0.f, 0.f);
    }
    __syncthreads();

    const int b = blockIdx.x & (NBATCH - 1);
    const int chunk = blockIdx.x / NBATCH;
    const int pix0 = chunk * (NPIX / SPLIT);
    const int base = tid * HSTRIDE;

    // E3^m, m=0..8 — independent scaling breaks the serial exp chain
    const float E3P[9] = {
        1.0f, 20.085536923187668f, 403.4287934927351f, 8103.083927575384f,
        162754.79141900392f, 3269017.372472111f, 65659969.13733051f,
        1318815734.4832146f, 26489122129.843472f };

    #pragma unroll
    for (int it = 0; it < ITERS; ++it) {
        const int pp = pix0 + (it * BLOCKT + tid) * PXPT;
        const float4* n4 = (const float4*)(normals + ((size_t)b * NPIX + pp) * 3);
        const float4* i4 = (const float4*)(inters  + ((size_t)b * NPIX + pp) * 3);
        const float4* f4 = (const float4*)(film + (size_t)pp * 3);
        const float4  c4 = *(const float4*)(cosm + pp);
        float4 n0 = n4[0], n1 = n4[1], n2 = n4[2];
        float4 i0 = i4[0], i1 = i4[1], i2 = i4[2];
        float4 f0 = f4[0], f1 = f4[1], f2 = f4[2];

        // gather 4 pixels into arrays (SoA in registers)
        float NX[4] = {n0.x, n0.w, n1.z, n2.y}, NY[4] = {n0.y, n1.x, n1.w, n2.z},
              NZ[4] = {n0.z, n1.y, n2.x, n2.w};
        float IX[4] = {i0.x, i0.w, i1.z, i2.y}, IY[4] = {i0.y, i1.x, i1.w, i2.z},
              IZ[4] = {i0.z, i1.y, i2.x, i2.w};
        float FX[4] = {f0.x, f0.w, f1.z, f2.y}, FY[4] = {f0.y, f1.x, f1.w, f2.z},
              FZ[4] = {f0.z, f1.y, f2.x, f2.w};
        float CM[4] = {c4.x, c4.y, c4.z, c4.w};

        int   K0[4];
        float W[4][8];   // final per-bin weights r*(s_m - s_{m+1})

        // Phase 1: all geometry + sigmoids + weights (4 independent chains -> ILP)
        #pragma unroll
        for (int p = 0; p < 4; ++p) {
            float dt = FX[p] * NX[p] + FY[p] * NY[p] + FZ[p] * NZ[p];
            dt = fminf(fmaxf(dt, 0.0f), 1.0f);
            float lx = IX[p] - 0.002f;
            float lxy2 = lx * lx + IY[p] * IY[p];
            float l2 = lxy2 + IZ[p] * IZ[p];
            float ld = __builtin_amdgcn_sqrtf(l2);
            float lm = __builtin_amdgcn_exp2f(
                lmask_c * lxy2 * __builtin_amdgcn_rcpf(IZ[p] * IZ[p]));
            float cm3 = CM[p] * CM[p] * CM[p];
            float r = dt * lm * kconst * cm3 * __builtin_amdgcn_rcpf(l2);
            float di = __builtin_amdgcn_sqrtf(
                IX[p] * IX[p] + IY[p] * IY[p] + IZ[p] * IZ[p]);
            float d = (di + ld) * half_inv_bin;     // depth in bin units

            int j0 = (int)floorf(d);
            j0 = j0 < 3 ? 3 : (j0 > 59 ? 59 : j0);
            int k0 = (j0 - 3) & ~3;                 // 4-aligned, in [0, 56]
            K0[p] = k0;
            float e0 = __builtin_amdgcn_exp2f(((float)k0 - d) * THREE_LOG2E);
            float S[9];
            #pragma unroll
            for (int m = 0; m < 9; ++m)             // independent fma+rcp
                S[m] = __builtin_amdgcn_rcpf(fmaf(e0, E3P[m], 1.0f));
            #pragma unroll
            for (int m = 0; m < 8; ++m)
                W[p][m] = r * (S[m] - S[m + 1]);
        }

        // Phase 2: per-pixel b128 RMW (ordered; same-thread windows may alias,
        // DS pipe is in-order per wave so read-after-write is safe)
        #pragma unroll
        for (int p = 0; p < 4; ++p) {
            float4* hp = (float4*)&hist[base + K0[p]];
            float4 a = hp[0], bb = hp[1];
            a.x  += W[p][0]; a.y  += W[p][1]; a.z  += W[p][2]; a.w  += W[p][3];
            bb.x += W[p][4]; bb.y += W[p][5]; bb.z += W[p][6]; bb.w += W[p][7];
            hp[0] = a; hp[1] = bb;
        }
    }
    __syncthreads();

    // 3-phase float4 reduction of 128 private histograms
    const int g = tid & 15;      // bin group: bins 4g..4g+3
    const int h = tid >> 4;      // hist subset start
    float4 acc = make_float4(0.f, 0.f, 0.f, 0.f);
    #pragma unroll
    for (int j = 0; j < 16; ++j) {
        float4 v = *(const float4*)&hist[(h + 8 * j) * HSTRIDE + 4 * g];
        acc.x += v.x; acc.y += v.y; acc.z += v.z; acc.w += v.w;
    }
    __syncthreads();
    *(float4*)&hist[tid * 4] = acc;   // partial[h][g] at dword h*64 + 4g
    __syncthreads();
    if (tid < 16) {
        float4 s4 = make_float4(0.f, 0.f, 0.f, 0.f);
        #pragma unroll
        for (int hh = 0; hh < 8; ++hh) {
            float4 v = *(const float4*)&hist[hh * 64 + tid * 4];
            s4.x += v.x; s4.y += v.y; s4.z += v.z; s4.w += v.w;
        }
        *(float4*)&ws[(size_t)blockIdx.x * NBINS + tid * 4] = s4;
    }
}

__global__ __launch_bounds__(256) void spad_reduce_kernel(
    const float* __restrict__ ws, float* __restrict__ out)
{
    const int o = blockIdx.x * 256 + threadIdx.x;  // 0..2047 -> (b, k)
    const int b = o >> 6;
    const int k = o & 63;
    float s = 0.0f;
    #pragma unroll
    for (int c = 0; c < SPLIT; ++c)
        s += ws[((size_t)(c * NBATCH + b)) * NBINS + k];
    out[o] = s;   // every element written -> no memset needed
}

extern "C" void kernel_launch(void* const* d_in, const int* in_sizes, int n_in,
                              void* d_out, int out_size, void* d_ws, size_t ws_size,
                              hipStream_t stream) {
    const float* normals = (const float*)d_in[0];
    const float* inters  = (const float*)d_in[1];
    const float* film    = (const float*)d_in[2];
    const float* cosm    = (const float*)d_in[3];
    float* out = (float*)d_out;
    float* ws  = (float*)d_ws;   // needs 1024*64*4 = 256 KiB

    // host-side double-precision constants (argument setup; capture-safe)
    const double fov_rad = 33.0 * M_PI / 180.0;
    const double width = 2.0 * tan(fov_rad / 2.0);
    const double kconst_d = width * width / M_PI / 65536.0;       // width^2/pi/R^2
    const double sig = tan(21.5 * M_PI / 180.0) / 1.4;
    const double log2e = 1.4426950408889634;
    const double lmask_c_d = -log2e / (2.0 * sig * sig);          // exp2 scale
    const double half_inv_bin_d = 0.5 / 0.0136;

    spad_hist_kernel<<<NBATCH * SPLIT, BLOCKT, 0, stream>>>(
        normals, inters, film, cosm, ws,
        (float)kconst_d, (float)lmask_c_d, (float)half_inv_bin_d);

    spad_reduce_kernel<<<(NBATCH * NBINS) / 256, 256, 0, stream>>>(ws, out);
}